// Round 4
// baseline (574.031 us; speedup 1.0000x reference)
//
#include <hip/hip_runtime.h>
#include <hip/hip_bf16.h>
#include <cmath>

#define T_ 512
#define B_ 32
#define S_ 512
#define D_ 512
#define D3_ 1536
#define NCH 16
#define CT (T_ / NCH)
static constexpr float LN_EPS = 1e-6f;
static constexpr float RSQRT_D = 0.044194173824159216f; // 1/sqrt(512)

typedef __attribute__((ext_vector_type(8))) __bf16 bf16x8;
typedef __attribute__((ext_vector_type(4))) float f32x4;

struct __align__(8) bfx4 { __hip_bfloat16 x, y, z, w; };

// ---------------- async global->LDS, 16B per lane ---------------------------
__device__ __forceinline__ void g2l16(const void* g, void* l) {
    __builtin_amdgcn_global_load_lds(
        (const __attribute__((address_space(1))) unsigned int*)g,
        (__attribute__((address_space(3))) unsigned int*)l, 16, 0, 0);
}

// 16-lane xor reductions (lanes sharing lane>>4 quad reduce over lane&15)
__device__ __forceinline__ float xr_sum16(float v) {
    v += __shfl_xor(v, 1); v += __shfl_xor(v, 2);
    v += __shfl_xor(v, 4); v += __shfl_xor(v, 8); return v;
}
__device__ __forceinline__ float xr_max16(float v) {
    v = fmaxf(v, __shfl_xor(v, 1)); v = fmaxf(v, __shfl_xor(v, 2));
    v = fmaxf(v, __shfl_xor(v, 4)); v = fmaxf(v, __shfl_xor(v, 8)); return v;
}

__device__ __forceinline__ float sigmoidf_(float x) {
    return 1.f / (1.f + __expf(-x));
}

// =============== K1: preact GEMM 128x128 (m97 structure) ====================
// A = prevb [16384,512] bf16, B = W_inT [1536,512] bf16.
// Writes preb bf16 [16384,1536] (LDS-repacked coalesced) + per-block row
// (sum,sumsq) partials for the 1536-wide LayerNorm.
__global__ __launch_bounds__(256) void gemm_pre(
    const __hip_bfloat16* __restrict__ A,
    const __hip_bfloat16* __restrict__ Bw,
    __hip_bfloat16* __restrict__ preb,
    float2* __restrict__ part)
{
    __shared__ char smem[16384];
    __hip_bfloat16* As = (__hip_bfloat16*)smem;
    __hip_bfloat16* Bs = (__hip_bfloat16*)(smem + 8192);

    const int m0 = blockIdx.y * 128, n0 = blockIdx.x * 128;
    const int tid = threadIdx.x, lane = tid & 63, w = tid >> 6;
    const int wm = (w >> 1) * 64, wn = (w & 1) * 64;
    const int srow = lane >> 2, skB = (lane & 3) * 16;
    const int q = lane >> 4, c = lane & 15;

    f32x4 acc[4][4];
#pragma unroll
    for (int i = 0; i < 4; i++)
#pragma unroll
        for (int j = 0; j < 4; j++) acc[i][j] = (f32x4)(0.0f);

    const char* ga0 = (const char*)(A + (long)(m0 + w * 16 + srow) * 512) + skB;
    const char* ga1 = (const char*)(A + (long)(m0 + (w + 4) * 16 + srow) * 512) + skB;
    const char* gb0 = (const char*)(Bw + (long)(n0 + w * 16 + srow) * 512) + skB;
    const char* gb1 = (const char*)(Bw + (long)(n0 + (w + 4) * 16 + srow) * 512) + skB;
    char* la0 = (char*)As + w * 1024 + lane * 16;
    char* la1 = (char*)As + (w + 4) * 1024 + lane * 16;
    char* lb0 = (char*)Bs + w * 1024 + lane * 16;
    char* lb1 = (char*)Bs + (w + 4) * 1024 + lane * 16;
    const char* Ar = (const char*)As + (wm + c) * 64 + q * 16;
    const char* Br = (const char*)Bs + (wn + c) * 64 + q * 16;

    for (int k0 = 0; k0 < 512; k0 += 32) {
        const long kb = (long)k0 * 2;
        g2l16(ga0 + kb, la0);
        g2l16(ga1 + kb, la1);
        g2l16(gb0 + kb, lb0);
        g2l16(gb1 + kb, lb1);
        __syncthreads();
        bf16x8 af[4], bfr[4];
#pragma unroll
        for (int i = 0; i < 4; i++) {
            af[i] = *(const bf16x8*)(Ar + i * 1024);
            bfr[i] = *(const bf16x8*)(Br + i * 1024);
        }
#pragma unroll
        for (int i = 0; i < 4; i++)
#pragma unroll
            for (int j = 0; j < 4; j++)
                acc[i][j] = __builtin_amdgcn_mfma_f32_16x16x32_bf16(
                    af[i], bfr[j], acc[i][j], 0, 0, 0);
        __syncthreads();
    }

    // ---- row stats partials (sum, sumsq over this block's 128 cols) ----
    float2* sred = (float2*)smem;        // [128][2]
#pragma unroll
    for (int i = 0; i < 4; i++)
#pragma unroll
        for (int r = 0; r < 4; r++) {
            float s = 0.f, qq = 0.f;
#pragma unroll
            for (int j = 0; j < 4; j++) {
                float v = acc[i][j][r]; s += v; qq += v * v;
            }
            s = xr_sum16(s); qq = xr_sum16(qq);
            if (c == 0) sred[(wm + i * 16 + q * 4 + r) * 2 + (w & 1)] =
                make_float2(s, qq);
        }
    __syncthreads();
    if ((w & 1) == 0 && c == 0) {
#pragma unroll
        for (int i = 0; i < 4; i++)
#pragma unroll
            for (int r = 0; r < 4; r++) {
                int row = wm + i * 16 + q * 4 + r;
                float2 a = sred[row * 2], b2 = sred[row * 2 + 1];
                part[(long)blockIdx.x * 16384 + m0 + row] =
                    make_float2(a.x + b2.x, a.y + b2.y);
            }
    }
    __syncthreads();

    // ---- bf16 store via LDS repack (2 passes of 64 rows x 128 cols) ----
    for (int p = 0; p < 2; p++) {
        if ((w >> 1) == p) {
#pragma unroll
            for (int i = 0; i < 4; i++)
#pragma unroll
                for (int j = 0; j < 4; j++)
#pragma unroll
                    for (int r = 0; r < 4; r++) {
                        int row = i * 16 + q * 4 + r;
                        int col = wn + j * 16 + c;
                        ((__hip_bfloat16*)smem)[row * 128 + col] =
                            __float2bfloat16(acc[i][j][r]);
                    }
        }
        __syncthreads();
#pragma unroll
        for (int rnd = 0; rnd < 4; rnd++) {
            int row = rnd * 16 + (tid >> 4);
            int ch = tid & 15;
            uint4 v = *(const uint4*)(smem + row * 256 + ch * 16);
            long grow = m0 + p * 64 + row;
            *(uint4*)((char*)preb + grow * 3072 + (long)n0 * 2 + ch * 16) = v;
        }
        __syncthreads();
    }
}

// =============== fused-row GEMM core: 64 rows x full N=512, K param =========
// A rows k-major (lda elems), B [512 n-rows][K] k-major (ldb elems).
// acc[m][j]: row = m*16 + (lane>>4)*4 + r, col = w*128 + j*16 + (lane&15).
__device__ __forceinline__ void rows_core(
    const __hip_bfloat16* A, long lda,
    const __hip_bfloat16* B, long ldb, int K,
    char* smem, f32x4 (&acc)[4][8])
{
    const int tid = threadIdx.x, lane = tid & 63, w = tid >> 6;
#pragma unroll
    for (int m = 0; m < 4; m++)
#pragma unroll
        for (int j = 0; j < 8; j++) acc[m][j] = (f32x4)(0.0f);

    const char* ga = (const char*)(A + (long)(w * 16 + (lane >> 2)) * lda) + (lane & 3) * 16;
    char* la = smem + w * 1024 + lane * 16;
    const char* gb = (const char*)(B + (long)(w * 128 + (lane >> 2)) * ldb) + (lane & 3) * 16;
    char* lb = smem + 4096 + w * 8192 + lane * 16;
    const long ldbB16 = (long)ldb * 32;   // 16 rows in bytes
    const char* Ar = smem + (lane & 15) * 64 + (lane >> 4) * 16;
    const char* Br = smem + 4096 + (w * 128 + (lane & 15)) * 64 + (lane >> 4) * 16;

    for (int k0 = 0; k0 < K; k0 += 32) {
        const long kb = (long)k0 * 2;
        g2l16(ga + kb, la);
#pragma unroll
        for (int s = 0; s < 8; s++) g2l16(gb + kb + s * ldbB16, lb + s * 1024);
        __syncthreads();
        bf16x8 af[4], bfr[8];
#pragma unroll
        for (int m = 0; m < 4; m++) af[m] = *(const bf16x8*)(Ar + m * 1024);
#pragma unroll
        for (int j = 0; j < 8; j++) bfr[j] = *(const bf16x8*)(Br + j * 1024);
#pragma unroll
        for (int m = 0; m < 4; m++)
#pragma unroll
            for (int j = 0; j < 8; j++)
                acc[m][j] = __builtin_amdgcn_mfma_f32_16x16x32_bf16(
                    af[m], bfr[j], acc[m][j], 0, 0, 0);
        __syncthreads();
    }
}

// =============== K2/K3/K6: GEMM + row LayerNorm -> bf16 (1KB rows) ==========
__global__ __launch_bounds__(256, 2) void gemm_ln(
    const __hip_bfloat16* __restrict__ A, long lda,
    const __hip_bfloat16* __restrict__ W,
    const float* __restrict__ g, const float* __restrict__ bb,
    __hip_bfloat16* __restrict__ out)
{
    __shared__ char smem[36864];
    const long m0 = (long)blockIdx.y * 64;
    f32x4 acc[4][8];
    rows_core(A + m0 * lda, lda, W, 512, 512, smem, acc);

    const int tid = threadIdx.x, lane = tid & 63, w = tid >> 6;
    const int q = lane >> 4, c = lane & 15;
    float2* sred = (float2*)smem;        // [64][4]
    float mean[4][4], rstd[4][4];
#pragma unroll
    for (int m = 0; m < 4; m++)
#pragma unroll
        for (int r = 0; r < 4; r++) {
            float s = 0.f, qq = 0.f;
#pragma unroll
            for (int j = 0; j < 8; j++) {
                float v = acc[m][j][r]; s += v; qq += v * v;
            }
            s = xr_sum16(s); qq = xr_sum16(qq);
            if (c == 0) sred[(m * 16 + q * 4 + r) * 4 + w] = make_float2(s, qq);
        }
    __syncthreads();
#pragma unroll
    for (int m = 0; m < 4; m++)
#pragma unroll
        for (int r = 0; r < 4; r++) {
            int row = m * 16 + q * 4 + r;
            float s = 0.f, qq = 0.f;
#pragma unroll
            for (int ww = 0; ww < 4; ww++) {
                float2 t = sred[row * 4 + ww]; s += t.x; qq += t.y;
            }
            float mn = s * (1.f / 512);
            mean[m][r] = mn;
            rstd[m][r] = rsqrtf(qq * (1.f / 512) - mn * mn + LN_EPS);
        }
    __syncthreads();
    float gv[8], bv[8];
#pragma unroll
    for (int j = 0; j < 8; j++) {
        int col = w * 128 + j * 16 + c;
        gv[j] = g[col]; bv[j] = bb[col];
    }
    for (int m = 0; m < 4; m++) {
#pragma unroll
        for (int j = 0; j < 8; j++)
#pragma unroll
            for (int r = 0; r < 4; r++) {
                int row = q * 4 + r;
                int col = w * 128 + j * 16 + c;
                float v = (acc[m][j][r] - mean[m][r]) * rstd[m][r] * gv[j] + bv[j];
                ((__hip_bfloat16*)smem)[row * 512 + col] = __float2bfloat16(v);
            }
        __syncthreads();
#pragma unroll
        for (int rnd = 0; rnd < 4; rnd++) {
            int row = rnd * 4 + w;
            uint4 v = *(const uint4*)(smem + row * 1024 + lane * 16);
            *(uint4*)((char*)out + (m0 + m * 16 + row) * 1024 + lane * 16) = v;
        }
        __syncthreads();
    }
}

// =============== K4: align GEMM + masked softmax ============================
// A = attninb rows t (per batch), B = pctxb[b]. Writes pattn fp32 [T,B,S]
// and pattnb bf16 [T,B,S].
__global__ __launch_bounds__(256, 2) void gemm_attn(
    const __hip_bfloat16* __restrict__ attninb,
    const __hip_bfloat16* __restrict__ pctxb,
    const int* __restrict__ mlen,
    float* __restrict__ pattn, __hip_bfloat16* __restrict__ pattnb)
{
    __shared__ char smem[36864];
    const int b = blockIdx.z;
    const long t0 = (long)blockIdx.y * 64;
    f32x4 acc[4][8];
    rows_core(attninb + (long)b * 512 + t0 * 16384, 16384,
              pctxb + (long)b * 262144, 512, 512, smem, acc);

    const int tid = threadIdx.x, lane = tid & 63, w = tid >> 6;
    const int q = lane >> 4, c = lane & 15;
    const int len = mlen[b];
    float* sred = (float*)smem;          // [64][4]

    float rmax[4][4];
#pragma unroll
    for (int m = 0; m < 4; m++)
#pragma unroll
        for (int r = 0; r < 4; r++) {
            float mx = -INFINITY;
#pragma unroll
            for (int j = 0; j < 8; j++) {
                int col = w * 128 + j * 16 + c;
                float v = acc[m][j][r] * RSQRT_D;
                acc[m][j][r] = v;
                if (col < len) mx = fmaxf(mx, v);
            }
            mx = xr_max16(mx);
            if (c == 0) sred[(m * 16 + q * 4 + r) * 4 + w] = mx;
        }
    __syncthreads();
#pragma unroll
    for (int m = 0; m < 4; m++)
#pragma unroll
        for (int r = 0; r < 4; r++) {
            int row = m * 16 + q * 4 + r;
            rmax[m][r] = fmaxf(fmaxf(sred[row * 4], sred[row * 4 + 1]),
                               fmaxf(sred[row * 4 + 2], sred[row * 4 + 3]));
        }
    __syncthreads();
    float rinv[4][4];
#pragma unroll
    for (int m = 0; m < 4; m++)
#pragma unroll
        for (int r = 0; r < 4; r++) {
            float s = 0.f;
#pragma unroll
            for (int j = 0; j < 8; j++) {
                int col = w * 128 + j * 16 + c;
                float e = (col < len) ? __expf(acc[m][j][r] - rmax[m][r]) : 0.f;
                acc[m][j][r] = e; s += e;
            }
            s = xr_sum16(s);
            if (c == 0) sred[(m * 16 + q * 4 + r) * 4 + w] = s;
        }
    __syncthreads();
#pragma unroll
    for (int m = 0; m < 4; m++)
#pragma unroll
        for (int r = 0; r < 4; r++) {
            int row = m * 16 + q * 4 + r;
            float s = sred[row * 4] + sred[row * 4 + 1] +
                      sred[row * 4 + 2] + sred[row * 4 + 3];
            rinv[m][r] = 1.f / s;
        }
    __syncthreads();

    // fp32 p_attn direct + bf16 repack
#pragma unroll
    for (int m = 0; m < 4; m++)
#pragma unroll
        for (int j = 0; j < 8; j++)
#pragma unroll
            for (int r = 0; r < 4; r++) {
                int row = m * 16 + q * 4 + r;
                int col = w * 128 + j * 16 + c;
                float p = acc[m][j][r] * rinv[m][r];
                acc[m][j][r] = p;
                pattn[((t0 + row) * 32 + b) * 512 + col] = p;
            }
    for (int m = 0; m < 4; m++) {
#pragma unroll
        for (int j = 0; j < 8; j++)
#pragma unroll
            for (int r = 0; r < 4; r++) {
                int row = q * 4 + r;
                int col = w * 128 + j * 16 + c;
                ((__hip_bfloat16*)smem)[row * 512 + col] =
                    __float2bfloat16(acc[m][j][r]);
            }
        __syncthreads();
#pragma unroll
        for (int rnd = 0; rnd < 4; rnd++) {
            int row = rnd * 4 + w;
            uint4 v = *(const uint4*)(smem + row * 1024 + lane * 16);
            *(uint4*)((char*)pattnb + ((t0 + m * 16 + row) * 32 + b) * 1024 +
                      lane * 16) = v;
        }
        __syncthreads();
    }
}

// =============== K5: attn_out GEMM (scale, bf16 out) ========================
__global__ __launch_bounds__(256, 2) void gemm_av(
    const __hip_bfloat16* __restrict__ pattnb,
    const __hip_bfloat16* __restrict__ pctxT,
    __hip_bfloat16* __restrict__ attnoutb)
{
    __shared__ char smem[36864];
    const int b = blockIdx.z;
    const long t0 = (long)blockIdx.y * 64;
    f32x4 acc[4][8];
    rows_core(pattnb + (long)b * 512 + t0 * 16384, 16384,
              pctxT + (long)b * 262144, 512, 512, smem, acc);

    const int tid = threadIdx.x, lane = tid & 63, w = tid >> 6;
    const int q = lane >> 4, c = lane & 15;
    for (int m = 0; m < 4; m++) {
#pragma unroll
        for (int j = 0; j < 8; j++)
#pragma unroll
            for (int r = 0; r < 4; r++) {
                int row = q * 4 + r;
                int col = w * 128 + j * 16 + c;
                ((__hip_bfloat16*)smem)[row * 512 + col] =
                    __float2bfloat16(acc[m][j][r] * RSQRT_D);
            }
        __syncthreads();
#pragma unroll
        for (int rnd = 0; rnd < 4; rnd++) {
            int row = rnd * 4 + w;
            uint4 v = *(const uint4*)(smem + row * 1024 + lane * 16);
            *(uint4*)((char*)attnoutb + ((t0 + m * 16 + row) * 32 + b) * 1024 +
                      lane * 16) = v;
        }
        __syncthreads();
    }
}

// =============== K7: h2 GEMM + LN + add t1 + tanh + highway gate ============
__global__ __launch_bounds__(256, 2) void gemm_fin(
    const __hip_bfloat16* __restrict__ attnoutb,
    const __hip_bfloat16* __restrict__ Wc,
    const __hip_bfloat16* __restrict__ h1n,
    const __hip_bfloat16* __restrict__ preb,
    const float2* __restrict__ stats,
    const float* __restrict__ g_c, const float* __restrict__ b_c,
    const float* __restrict__ g_pre, const float* __restrict__ b_pre,
    const float* __restrict__ prev, float* __restrict__ out)
{
    __shared__ char smem[36864];
    const long m0 = (long)blockIdx.y * 64;
    f32x4 acc[4][8];
    rows_core(attnoutb + m0 * 512, 512, Wc, 512, 512, smem, acc);

    const int tid = threadIdx.x, lane = tid & 63, w = tid >> 6;
    const int q = lane >> 4, c = lane & 15;
    float2* sred = (float2*)smem;        // [64][4]
#pragma unroll
    for (int m = 0; m < 4; m++)
#pragma unroll
        for (int r = 0; r < 4; r++) {
            float s = 0.f, qq = 0.f;
#pragma unroll
            for (int j = 0; j < 8; j++) {
                float v = acc[m][j][r]; s += v; qq += v * v;
            }
            s = xr_sum16(s); qq = xr_sum16(qq);
            if (c == 0) sred[(m * 16 + q * 4 + r) * 4 + w] = make_float2(s, qq);
        }
    __syncthreads();
    float gcv[8], bcv[8], gpv[8], bpv[8];
#pragma unroll
    for (int j = 0; j < 8; j++) {
        int col = w * 128 + j * 16 + c;
        gcv[j] = g_c[col]; bcv[j] = b_c[col];
        gpv[j] = g_pre[512 + col]; bpv[j] = b_pre[512 + col];
    }
    for (int m = 0; m < 4; m++) {
#pragma unroll
        for (int r = 0; r < 4; r++) {
            int row = m * 16 + q * 4 + r;
            float s = 0.f, qq = 0.f;
#pragma unroll
            for (int ww = 0; ww < 4; ww++) {
                float2 t = sred[row * 4 + ww]; s += t.x; qq += t.y;
            }
            float mn = s * (1.f / 512);
            float rs = rsqrtf(qq * (1.f / 512) - mn * mn + LN_EPS);
            long rowg = m0 + row;
            float2 sh = stats[rowg];
#pragma unroll
            for (int j = 0; j < 8; j++) {
                int col = w * 128 + j * 16 + c;
                float t2 = (acc[m][j][r] - mn) * rs * gcv[j] + bcv[j];
                float t1 = __bfloat162float(h1n[rowg * 512 + col]);
                float hraw = __bfloat162float(preb[rowg * 1536 + 512 + col]);
                float hg = sigmoidf_((hraw - sh.x) * sh.y * gpv[j] + bpv[j]);
                float pv = prev[rowg * 512 + col];
                float o = tanhf(t1 + t2);
                out[rowg * 512 + col] = (1.f - hg) * o + hg * pv;
            }
        }
    }
}

// =============== small kernels ==============================================
__global__ __launch_bounds__(256) void cvt4(
    const float* __restrict__ x, __hip_bfloat16* __restrict__ y, int n4)
{
    int i = blockIdx.x * 256 + threadIdx.x;
    if (i >= n4) return;
    float4 v = ((const float4*)x)[i];
    bfx4 o;
    o.x = __float2bfloat16(v.x); o.y = __float2bfloat16(v.y);
    o.z = __float2bfloat16(v.z); o.w = __float2bfloat16(v.w);
    ((bfx4*)y)[i] = o;
}

__global__ __launch_bounds__(256) void wtrans(
    const float* __restrict__ w0, const float* __restrict__ w1,
    const float* __restrict__ w2, const float* __restrict__ w3,
    const float* __restrict__ w4, __hip_bfloat16* __restrict__ WT)
{
    int z = blockIdx.z;
    const float* W; long off; int N;
    if (z == 0)      { W = w0; off = 0;                N = 1536; }
    else if (z == 1) { W = w1; off = 786432;           N = 512; }
    else if (z == 2) { W = w2; off = 786432 + 262144;  N = 512; }
    else if (z == 3) { W = w3; off = 786432 + 524288;  N = 512; }
    else             { W = w4; off = 786432 + 786432;  N = 512; }
    int n0 = blockIdx.x * 32, k0 = blockIdx.y * 32;
    if (n0 >= N) return;
    __shared__ float t[32][33];
    int tx = threadIdx.x & 31, ty = threadIdx.x >> 5;
#pragma unroll
    for (int i = 0; i < 4; i++)
        t[ty + i * 8][tx] = W[(long)(k0 + ty + i * 8) * N + n0 + tx];
    __syncthreads();
    __hip_bfloat16* O = WT + off;
#pragma unroll
    for (int i = 0; i < 4; i++)
        O[(long)(n0 + ty + i * 8) * 512 + k0 + tx] =
            __float2bfloat16(t[tx][ty + i * 8]);
}

__global__ __launch_bounds__(256) void ptrans(
    const __hip_bfloat16* __restrict__ src, __hip_bfloat16* __restrict__ dst)
{
    long boff = (long)blockIdx.z * (S_ * D_);
    int d0 = blockIdx.x * 32, s0 = blockIdx.y * 32;
    __shared__ __hip_bfloat16 t[32][34];
    int tx = threadIdx.x & 31, ty = threadIdx.x >> 5;
#pragma unroll
    for (int i = 0; i < 4; i++)
        t[ty + i * 8][tx] = src[boff + (long)(s0 + ty + i * 8) * D_ + d0 + tx];
    __syncthreads();
#pragma unroll
    for (int i = 0; i < 4; i++)
        dst[boff + (long)(d0 + ty + i * 8) * S_ + s0 + tx] = t[tx][ty + i * 8];
}

__global__ __launch_bounds__(256) void stats_fin(
    const float2* __restrict__ part, float2* __restrict__ stats)
{
    int r = blockIdx.x * 256 + threadIdx.x;
    float s = 0.f, qq = 0.f;
#pragma unroll
    for (int cb = 0; cb < 12; cb++) {
        float2 v = part[(long)cb * 16384 + r]; s += v.x; qq += v.y;
    }
    float m = s * (1.f / 1536);
    float rs = rsqrtf(qq * (1.f / 1536) - m * m + LN_EPS);
    stats[r] = make_float2(m, rs);
}

// ---------------- chunked SRU scan with inline LN ---------------------------
__global__ __launch_bounds__(256) void scan_part1(
    const __hip_bfloat16* __restrict__ preb, const float2* __restrict__ stats,
    const float* __restrict__ gpre, const float* __restrict__ bpre,
    float* __restrict__ Ap, float* __restrict__ Bp)
{
    int idx = blockIdx.x * 256 + threadIdx.x;   // b*512+d
    int b = idx >> 9, d = idx & 511;
    int ch = blockIdx.y;
    float gz = gpre[d], bz = bpre[d];
    float gp = gpre[1024 + d], bpv = bpre[1024 + d];
    float A = 1.f, s = 0.f;
    for (int t = ch * CT; t < (ch + 1) * CT; t++) {
        long row = (long)t * 32 + b;
        float2 st = stats[row];
        float zr = __bfloat162float(preb[row * 1536 + d]);
        float pr = __bfloat162float(preb[row * 1536 + 1024 + d]);
        float z = sigmoidf_((zr - st.x) * st.y * gz + bz);
        float pl = (pr - st.x) * st.y * gp + bpv;
        float a = 1.f - z;
        A *= a;
        s = a * s + z * pl;
    }
    Ap[ch * 16384 + idx] = A;
    Bp[ch * 16384 + idx] = s;
}

__global__ __launch_bounds__(256) void scan_part2(
    const float* __restrict__ Ap, const float* __restrict__ Bp,
    const float* __restrict__ h0, float* __restrict__ sin_,
    float* __restrict__ hlast)
{
    int idx = blockIdx.x * 256 + threadIdx.x;
    float s = h0[idx];
    for (int ch = 0; ch < NCH; ch++) {
        sin_[ch * 16384 + idx] = s;
        s = Ap[ch * 16384 + idx] * s + Bp[ch * 16384 + idx];
    }
    hlast[idx] = s;
}

__global__ __launch_bounds__(256) void scan_part3(
    const __hip_bfloat16* __restrict__ preb, const float2* __restrict__ stats,
    const float* __restrict__ gpre, const float* __restrict__ bpre,
    const float* __restrict__ sin_, __hip_bfloat16* __restrict__ ssb)
{
    int idx = blockIdx.x * 256 + threadIdx.x;
    int b = idx >> 9, d = idx & 511;
    int ch = blockIdx.y;
    float gz = gpre[d], bz = bpre[d];
    float gp = gpre[1024 + d], bpv = bpre[1024 + d];
    float s = sin_[ch * 16384 + idx];
    for (int t = ch * CT; t < (ch + 1) * CT; t++) {
        long row = (long)t * 32 + b;
        float2 st = stats[row];
        float zr = __bfloat162float(preb[row * 1536 + d]);
        float pr = __bfloat162float(preb[row * 1536 + 1024 + d]);
        float z = sigmoidf_((zr - st.x) * st.y * gz + bz);
        float pl = (pr - st.x) * st.y * gp + bpv;
        s += z * (pl - s);
        ssb[(long)t * 16384 + idx] = __float2bfloat16(s);
    }
}

extern "C" void kernel_launch(void* const* d_in, const int* in_sizes, int n_in,
                              void* d_out, int out_size, void* d_ws, size_t ws_size,
                              hipStream_t stream) {
    const float* prev  = (const float*)d_in[0];
    const float* hid0  = (const float*)d_in[1];
    const float* enc   = (const float*)d_in[2];
    const int*   mlen  = (const int*)  d_in[3];
    const float* W_in  = (const float*)d_in[4];
    const float* W_enc = (const float*)d_in[5];
    const float* W_att = (const float*)d_in[6];
    const float* W_hid = (const float*)d_in[7];
    const float* W_ctx = (const float*)d_in[8];
    const float* g_pre = (const float*)d_in[9];
    const float* b_pre = (const float*)d_in[10];
    const float* g_enc = (const float*)d_in[11];
    const float* b_enc = (const float*)d_in[12];
    const float* g_att = (const float*)d_in[13];
    const float* b_att = (const float*)d_in[14];
    const float* g_h   = (const float*)d_in[15];
    const float* b_h   = (const float*)d_in[16];
    const float* g_c   = (const float*)d_in[17];
    const float* b_c   = (const float*)d_in[18];

    float* out   = (float*)d_out;                 // [T,B,D]
    float* hlast = out + (long)T_ * B_ * D_;      // [B,D]
    float* pattn = hlast + (long)B_ * D_;         // [T,B,S]

    char* ws = (char*)d_ws;
    __hip_bfloat16* preb    = (__hip_bfloat16*)(ws);               // 48MB
    __hip_bfloat16* WT      = (__hip_bfloat16*)(ws + 50331648);    // 4MB
    __hip_bfloat16* prevb   = (__hip_bfloat16*)(ws + 54525952);    // 16MB
    __hip_bfloat16* encb    = (__hip_bfloat16*)(ws + 71303168);    // 16MB
    __hip_bfloat16* pctxb   = (__hip_bfloat16*)(ws + 88080384);    // 16MB
    __hip_bfloat16* pctxT   = (__hip_bfloat16*)(ws + 104857600);   // 16MB
    __hip_bfloat16* ssb     = (__hip_bfloat16*)(ws + 121634816);   // 16MB
    __hip_bfloat16* attninb = (__hip_bfloat16*)(ws + 138412032);   // 16MB
    __hip_bfloat16* pattnb  = (__hip_bfloat16*)(ws + 155189248);   // 16MB
    __hip_bfloat16* attnoutb= (__hip_bfloat16*)(ws + 171966464);   // 16MB
    __hip_bfloat16* h1n     = (__hip_bfloat16*)(ws + 188743680);   // 16MB
    float2* part            = (float2*)(ws + 205520896);           // 1.5MB
    float2* stats           = (float2*)(ws + 207093760);           // 128KB
    // scan buffers: each [NCH][16384] floats = 1 MB — MUST be 1 MB apart
    // (round-3 bug: 64 KB spacing aliased scanA[ch>=1] onto scanB/sinb)
    float* scanA            = (float*)(ws + 207224832);            // 1MB
    float* scanB            = (float*)(ws + 208273408);            // 1MB
    float* sinb             = (float*)(ws + 209321984);            // 1MB

    const __hip_bfloat16* W_encT = WT + 786432;
    const __hip_bfloat16* W_attT = WT + 786432 + 262144;
    const __hip_bfloat16* W_hidT = WT + 786432 + 524288;
    const __hip_bfloat16* W_ctxT = WT + 786432 + 786432;

    dim3 blk(256);

    // inputs -> bf16
    cvt4<<<8192, blk, 0, stream>>>(prev, prevb, 2097152);
    cvt4<<<8192, blk, 0, stream>>>(enc, encb, 2097152);
    wtrans<<<dim3(48, 16, 5), blk, 0, stream>>>(W_in, W_enc, W_att, W_hid,
                                                W_ctx, WT);

    // K1: preact GEMM -> preb bf16 + LN partials
    gemm_pre<<<dim3(12, 128), blk, 0, stream>>>(prevb, WT, preb, part);
    stats_fin<<<64, blk, 0, stream>>>(part, stats);

    // SRU scan (inline LN on preb)
    scan_part1<<<dim3(64, NCH), blk, 0, stream>>>(preb, stats, g_pre, b_pre,
                                                  scanA, scanB);
    scan_part2<<<64, blk, 0, stream>>>(scanA, scanB, hid0, sinb, hlast);
    scan_part3<<<dim3(64, NCH), blk, 0, stream>>>(preb, stats, g_pre, b_pre,
                                                  sinb, ssb);

    // K2: pctx = LN(enc @ W_enc) -> bf16 (+ transposed copy)
    gemm_ln<<<dim3(1, 256), blk, 0, stream>>>(encb, 512, W_encT, g_enc, b_enc,
                                              pctxb);
    ptrans<<<dim3(16, 16, 32), blk, 0, stream>>>(pctxb, pctxT);

    // K3: attn_in = LN(ss @ W_attn_in) -> bf16
    gemm_ln<<<dim3(1, 256), blk, 0, stream>>>(ssb, 512, W_attT, g_att, b_att,
                                              attninb);

    // K4: align + masked softmax -> pattn fp32 + pattnb bf16
    gemm_attn<<<dim3(1, 8, 32), blk, 0, stream>>>(attninb, pctxb, mlen,
                                                  pattn, pattnb);

    // K5: attn_out = av @ pctx / sqrt(d) -> bf16
    gemm_av<<<dim3(1, 8, 32), blk, 0, stream>>>(pattnb, pctxT, attnoutb);

    // K6: h1n = LN(ss @ W_hidden) -> bf16
    gemm_ln<<<dim3(1, 256), blk, 0, stream>>>(ssb, 512, W_hidT, g_h, b_h, h1n);

    // K7: out = (1-hg)*tanh(h1n + LN(attn_out @ W_ctx)) + hg*prev
    gemm_fin<<<dim3(1, 256), blk, 0, stream>>>(attnoutb, W_ctxT, h1n, preb,
                                               stats, g_c, b_c, g_pre, b_pre,
                                               prev, out);
}

// Round 5
// 463.048 us; speedup vs baseline: 1.2397x; 1.2397x over previous
//
#include <hip/hip_runtime.h>
#include <hip/hip_bf16.h>
#include <cmath>

#define T_ 512
#define B_ 32
#define S_ 512
#define D_ 512
#define D3_ 1536
#define NCH 16
#define CT (T_ / NCH)
static constexpr float LN_EPS = 1e-6f;
static constexpr float RSQRT_D = 0.044194173824159216f; // 1/sqrt(512)

typedef __attribute__((ext_vector_type(8))) __bf16 bf16x8;
typedef __attribute__((ext_vector_type(4))) float f32x4;

struct __align__(8) bfx4 { __hip_bfloat16 x, y, z, w; };

// ---------------- async global->LDS, 16B per lane ---------------------------
__device__ __forceinline__ void g2l16(const void* g, void* l) {
    __builtin_amdgcn_global_load_lds(
        (const __attribute__((address_space(1))) unsigned int*)g,
        (__attribute__((address_space(3))) unsigned int*)l, 16, 0, 0);
}

// 16-lane xor reductions (lanes sharing lane>>4 quad reduce over lane&15)
__device__ __forceinline__ float xr_sum16(float v) {
    v += __shfl_xor(v, 1); v += __shfl_xor(v, 2);
    v += __shfl_xor(v, 4); v += __shfl_xor(v, 8); return v;
}
__device__ __forceinline__ float xr_max16(float v) {
    v = fmaxf(v, __shfl_xor(v, 1)); v = fmaxf(v, __shfl_xor(v, 2));
    v = fmaxf(v, __shfl_xor(v, 4)); v = fmaxf(v, __shfl_xor(v, 8)); return v;
}

__device__ __forceinline__ float sigmoidf_(float x) {
    return 1.f / (1.f + __expf(-x));
}

// =============== K1: preact GEMM 128x128 (m97 structure) ====================
// A = prevb [16384,512] bf16, B = W_inT [1536,512] bf16.
// Writes preb bf16 [16384,1536] (LDS-repacked coalesced) + per-block row
// (sum,sumsq) partials for the 1536-wide LayerNorm.
__global__ __launch_bounds__(256) void gemm_pre(
    const __hip_bfloat16* __restrict__ A,
    const __hip_bfloat16* __restrict__ Bw,
    __hip_bfloat16* __restrict__ preb,
    float2* __restrict__ part)
{
    __shared__ char smem[16384];
    __hip_bfloat16* As = (__hip_bfloat16*)smem;
    __hip_bfloat16* Bs = (__hip_bfloat16*)(smem + 8192);

    const int m0 = blockIdx.y * 128, n0 = blockIdx.x * 128;
    const int tid = threadIdx.x, lane = tid & 63, w = tid >> 6;
    const int wm = (w >> 1) * 64, wn = (w & 1) * 64;
    const int srow = lane >> 2, skB = (lane & 3) * 16;
    const int q = lane >> 4, c = lane & 15;

    f32x4 acc[4][4];
#pragma unroll
    for (int i = 0; i < 4; i++)
#pragma unroll
        for (int j = 0; j < 4; j++) acc[i][j] = (f32x4)(0.0f);

    const char* ga0 = (const char*)(A + (long)(m0 + w * 16 + srow) * 512) + skB;
    const char* ga1 = (const char*)(A + (long)(m0 + (w + 4) * 16 + srow) * 512) + skB;
    const char* gb0 = (const char*)(Bw + (long)(n0 + w * 16 + srow) * 512) + skB;
    const char* gb1 = (const char*)(Bw + (long)(n0 + (w + 4) * 16 + srow) * 512) + skB;
    char* la0 = (char*)As + w * 1024 + lane * 16;
    char* la1 = (char*)As + (w + 4) * 1024 + lane * 16;
    char* lb0 = (char*)Bs + w * 1024 + lane * 16;
    char* lb1 = (char*)Bs + (w + 4) * 1024 + lane * 16;
    const char* Ar = (const char*)As + (wm + c) * 64 + q * 16;
    const char* Br = (const char*)Bs + (wn + c) * 64 + q * 16;

    for (int k0 = 0; k0 < 512; k0 += 32) {
        const long kb = (long)k0 * 2;
        g2l16(ga0 + kb, la0);
        g2l16(ga1 + kb, la1);
        g2l16(gb0 + kb, lb0);
        g2l16(gb1 + kb, lb1);
        __syncthreads();
        bf16x8 af[4], bfr[4];
#pragma unroll
        for (int i = 0; i < 4; i++) {
            af[i] = *(const bf16x8*)(Ar + i * 1024);
            bfr[i] = *(const bf16x8*)(Br + i * 1024);
        }
#pragma unroll
        for (int i = 0; i < 4; i++)
#pragma unroll
            for (int j = 0; j < 4; j++)
                acc[i][j] = __builtin_amdgcn_mfma_f32_16x16x32_bf16(
                    af[i], bfr[j], acc[i][j], 0, 0, 0);
        __syncthreads();
    }

    // ---- row stats partials (sum, sumsq over this block's 128 cols) ----
    float2* sred = (float2*)smem;        // [128][2]
#pragma unroll
    for (int i = 0; i < 4; i++)
#pragma unroll
        for (int r = 0; r < 4; r++) {
            float s = 0.f, qq = 0.f;
#pragma unroll
            for (int j = 0; j < 4; j++) {
                float v = acc[i][j][r]; s += v; qq += v * v;
            }
            s = xr_sum16(s); qq = xr_sum16(qq);
            if (c == 0) sred[(wm + i * 16 + q * 4 + r) * 2 + (w & 1)] =
                make_float2(s, qq);
        }
    __syncthreads();
    if ((w & 1) == 0 && c == 0) {
#pragma unroll
        for (int i = 0; i < 4; i++)
#pragma unroll
            for (int r = 0; r < 4; r++) {
                int row = wm + i * 16 + q * 4 + r;
                float2 a = sred[row * 2], b2 = sred[row * 2 + 1];
                part[(long)blockIdx.x * 16384 + m0 + row] =
                    make_float2(a.x + b2.x, a.y + b2.y);
            }
    }
    __syncthreads();

    // ---- bf16 store via LDS repack (2 passes of 64 rows x 128 cols) ----
    for (int p = 0; p < 2; p++) {
        if ((w >> 1) == p) {
#pragma unroll
            for (int i = 0; i < 4; i++)
#pragma unroll
                for (int j = 0; j < 4; j++)
#pragma unroll
                    for (int r = 0; r < 4; r++) {
                        int row = i * 16 + q * 4 + r;
                        int col = wn + j * 16 + c;
                        ((__hip_bfloat16*)smem)[row * 128 + col] =
                            __float2bfloat16(acc[i][j][r]);
                    }
        }
        __syncthreads();
#pragma unroll
        for (int rnd = 0; rnd < 4; rnd++) {
            int row = rnd * 16 + (tid >> 4);
            int ch = tid & 15;
            uint4 v = *(const uint4*)(smem + row * 256 + ch * 16);
            long grow = m0 + p * 64 + row;
            *(uint4*)((char*)preb + grow * 3072 + (long)n0 * 2 + ch * 16) = v;
        }
        __syncthreads();
    }
}

// =============== fused-row GEMM core: 32 rows x full N=512, K=512 ===========
// acc[2][8] = 64 VGPR/lane (round-4's acc[4][8]=128 spilled to scratch:
// 552 MB WRITE_SIZE on gemm_fin. 32-row blocks keep acc in the AGPR budget).
// A rows k-major (lda elems), B [512 n-rows][K=512] k-major (ldb elems).
// acc[m][j]: row = m*16 + (lane>>4)*4 + r, col = w*128 + j*16 + (lane&15).
__device__ __forceinline__ void rows_core32(
    const __hip_bfloat16* A, long lda,
    const __hip_bfloat16* B, long ldb,
    char* smem, f32x4 (&acc)[2][8])
{
    const int tid = threadIdx.x, lane = tid & 63, w = tid >> 6;
#pragma unroll
    for (int m = 0; m < 2; m++)
#pragma unroll
        for (int j = 0; j < 8; j++) acc[m][j] = (f32x4)(0.0f);

    // A: 2 chunks of 16 rows (waves 0,1); B: 32 chunks, 8 per wave
    const char* ga = (const char*)(A + (long)(w * 16 + (lane >> 2)) * lda) + (lane & 3) * 16;
    char* la = smem + w * 1024 + lane * 16;
    const char* gb = (const char*)(B + (long)(w * 128 + (lane >> 2)) * ldb) + (lane & 3) * 16;
    char* lb = smem + 2048 + w * 8192 + lane * 16;
    const long ldbB16 = (long)ldb * 32;   // 16 B-rows in bytes
    const char* Ar = smem + (lane & 15) * 64 + (lane >> 4) * 16;
    const char* Br = smem + 2048 + (w * 128 + (lane & 15)) * 64 + (lane >> 4) * 16;

    for (int k0 = 0; k0 < 512; k0 += 32) {
        const long kb = (long)k0 * 2;
        if (w < 2) g2l16(ga + kb, la);
#pragma unroll
        for (int s = 0; s < 8; s++) g2l16(gb + kb + s * ldbB16, lb + s * 1024);
        __syncthreads();
        bf16x8 af[2], bfr[8];
#pragma unroll
        for (int m = 0; m < 2; m++) af[m] = *(const bf16x8*)(Ar + m * 1024);
#pragma unroll
        for (int j = 0; j < 8; j++) bfr[j] = *(const bf16x8*)(Br + j * 1024);
#pragma unroll
        for (int m = 0; m < 2; m++)
#pragma unroll
            for (int j = 0; j < 8; j++)
                acc[m][j] = __builtin_amdgcn_mfma_f32_16x16x32_bf16(
                    af[m], bfr[j], acc[m][j], 0, 0, 0);
        __syncthreads();
    }
}

// =============== K2/K3/K6: GEMM + row LayerNorm -> bf16 (1KB rows) ==========
__global__ __launch_bounds__(256, 2) void gemm_ln(
    const __hip_bfloat16* __restrict__ A, long lda,
    const __hip_bfloat16* __restrict__ W,
    const float* __restrict__ g, const float* __restrict__ bb,
    __hip_bfloat16* __restrict__ out)
{
    __shared__ char smem[34816];
    const long m0 = (long)blockIdx.y * 32;
    f32x4 acc[2][8];
    rows_core32(A + m0 * lda, lda, W, 512, smem, acc);

    const int tid = threadIdx.x, lane = tid & 63, w = tid >> 6;
    const int q = lane >> 4, c = lane & 15;
    float2* sred = (float2*)smem;        // [32][4]
#pragma unroll
    for (int m = 0; m < 2; m++)
#pragma unroll
        for (int r = 0; r < 4; r++) {
            float s = 0.f, qq = 0.f;
#pragma unroll
            for (int j = 0; j < 8; j++) {
                float v = acc[m][j][r]; s += v; qq += v * v;
            }
            s = xr_sum16(s); qq = xr_sum16(qq);
            if (c == 0) sred[(m * 16 + q * 4 + r) * 4 + w] = make_float2(s, qq);
        }
    __syncthreads();
    float mean[2][4], rstd[2][4];
#pragma unroll
    for (int m = 0; m < 2; m++)
#pragma unroll
        for (int r = 0; r < 4; r++) {
            int row = m * 16 + q * 4 + r;
            float s = 0.f, qq = 0.f;
#pragma unroll
            for (int ww = 0; ww < 4; ww++) {
                float2 t = sred[row * 4 + ww]; s += t.x; qq += t.y;
            }
            float mn = s * (1.f / 512);
            mean[m][r] = mn;
            rstd[m][r] = rsqrtf(qq * (1.f / 512) - mn * mn + LN_EPS);
        }
    __syncthreads();
#pragma unroll
    for (int m = 0; m < 2; m++)
#pragma unroll
        for (int j = 0; j < 8; j++) {
            int col = w * 128 + j * 16 + c;
            float gv = g[col], bv = bb[col];
#pragma unroll
            for (int r = 0; r < 4; r++) {
                int row = m * 16 + q * 4 + r;
                float v = (acc[m][j][r] - mean[m][r]) * rstd[m][r] * gv + bv;
                ((__hip_bfloat16*)smem)[row * 512 + col] = __float2bfloat16(v);
            }
        }
    __syncthreads();
#pragma unroll
    for (int rnd = 0; rnd < 8; rnd++) {
        int row = rnd * 4 + w;
        uint4 v = *(const uint4*)(smem + row * 1024 + lane * 16);
        *(uint4*)((char*)out + (m0 + row) * 1024 + lane * 16) = v;
    }
}

// =============== K4: align GEMM + masked softmax ============================
__global__ __launch_bounds__(256, 2) void gemm_attn(
    const __hip_bfloat16* __restrict__ attninb,
    const __hip_bfloat16* __restrict__ pctxb,
    const int* __restrict__ mlen,
    float* __restrict__ pattn, __hip_bfloat16* __restrict__ pattnb)
{
    __shared__ char smem[34816];
    const int b = blockIdx.z;
    const long t0 = (long)blockIdx.y * 32;
    f32x4 acc[2][8];
    rows_core32(attninb + (long)b * 512 + t0 * 16384, 16384,
                pctxb + (long)b * 262144, 512, smem, acc);

    const int tid = threadIdx.x, lane = tid & 63, w = tid >> 6;
    const int q = lane >> 4, c = lane & 15;
    const int len = mlen[b];
    float* sred = (float*)smem;          // [32][4]

#pragma unroll
    for (int m = 0; m < 2; m++)
#pragma unroll
        for (int r = 0; r < 4; r++) {
            float mx = -INFINITY;
#pragma unroll
            for (int j = 0; j < 8; j++) {
                int col = w * 128 + j * 16 + c;
                float v = acc[m][j][r] * RSQRT_D;
                acc[m][j][r] = v;
                if (col < len) mx = fmaxf(mx, v);
            }
            mx = xr_max16(mx);
            if (c == 0) sred[(m * 16 + q * 4 + r) * 4 + w] = mx;
        }
    __syncthreads();
    float rmax[2][4];
#pragma unroll
    for (int m = 0; m < 2; m++)
#pragma unroll
        for (int r = 0; r < 4; r++) {
            int row = m * 16 + q * 4 + r;
            rmax[m][r] = fmaxf(fmaxf(sred[row * 4], sred[row * 4 + 1]),
                               fmaxf(sred[row * 4 + 2], sred[row * 4 + 3]));
        }
    __syncthreads();
#pragma unroll
    for (int m = 0; m < 2; m++)
#pragma unroll
        for (int r = 0; r < 4; r++) {
            float s = 0.f;
#pragma unroll
            for (int j = 0; j < 8; j++) {
                int col = w * 128 + j * 16 + c;
                float e = (col < len) ? __expf(acc[m][j][r] - rmax[m][r]) : 0.f;
                acc[m][j][r] = e; s += e;
            }
            s = xr_sum16(s);
            if (c == 0) sred[(m * 16 + q * 4 + r) * 4 + w] = s;
        }
    __syncthreads();
    float rinv[2][4];
#pragma unroll
    for (int m = 0; m < 2; m++)
#pragma unroll
        for (int r = 0; r < 4; r++) {
            int row = m * 16 + q * 4 + r;
            rinv[m][r] = 1.f / (sred[row * 4] + sred[row * 4 + 1] +
                                sred[row * 4 + 2] + sred[row * 4 + 3]);
        }
    __syncthreads();

    // fp32 p_attn direct + bf16 repack
#pragma unroll
    for (int m = 0; m < 2; m++)
#pragma unroll
        for (int j = 0; j < 8; j++)
#pragma unroll
            for (int r = 0; r < 4; r++) {
                int row = m * 16 + q * 4 + r;
                int col = w * 128 + j * 16 + c;
                float p = acc[m][j][r] * rinv[m][r];
                acc[m][j][r] = p;
                pattn[((t0 + row) * 32 + b) * 512 + col] = p;
                ((__hip_bfloat16*)smem)[row * 512 + col] = __float2bfloat16(p);
            }
    __syncthreads();
#pragma unroll
    for (int rnd = 0; rnd < 8; rnd++) {
        int row = rnd * 4 + w;
        uint4 v = *(const uint4*)(smem + row * 1024 + lane * 16);
        *(uint4*)((char*)pattnb + ((t0 + row) * 32 + b) * 1024 + lane * 16) = v;
    }
}

// =============== K5: attn_out GEMM (scale, bf16 out) ========================
__global__ __launch_bounds__(256, 2) void gemm_av(
    const __hip_bfloat16* __restrict__ pattnb,
    const __hip_bfloat16* __restrict__ pctxT,
    __hip_bfloat16* __restrict__ attnoutb)
{
    __shared__ char smem[34816];
    const int b = blockIdx.z;
    const long t0 = (long)blockIdx.y * 32;
    f32x4 acc[2][8];
    rows_core32(pattnb + (long)b * 512 + t0 * 16384, 16384,
                pctxT + (long)b * 262144, 512, smem, acc);

    const int tid = threadIdx.x, lane = tid & 63, w = tid >> 6;
    const int q = lane >> 4, c = lane & 15;
#pragma unroll
    for (int m = 0; m < 2; m++)
#pragma unroll
        for (int j = 0; j < 8; j++)
#pragma unroll
            for (int r = 0; r < 4; r++) {
                int row = m * 16 + q * 4 + r;
                int col = w * 128 + j * 16 + c;
                ((__hip_bfloat16*)smem)[row * 512 + col] =
                    __float2bfloat16(acc[m][j][r] * RSQRT_D);
            }
    __syncthreads();
#pragma unroll
    for (int rnd = 0; rnd < 8; rnd++) {
        int row = rnd * 4 + w;
        uint4 v = *(const uint4*)(smem + row * 1024 + lane * 16);
        *(uint4*)((char*)attnoutb + ((t0 + row) * 32 + b) * 1024 + lane * 16) = v;
    }
}

// =============== K7: h2 GEMM + LN + add t1 + tanh + highway gate ============
__global__ __launch_bounds__(256, 2) void gemm_fin(
    const __hip_bfloat16* __restrict__ attnoutb,
    const __hip_bfloat16* __restrict__ Wc,
    const __hip_bfloat16* __restrict__ h1n,
    const __hip_bfloat16* __restrict__ preb,
    const float2* __restrict__ stats,
    const float* __restrict__ g_c, const float* __restrict__ b_c,
    const float* __restrict__ g_pre, const float* __restrict__ b_pre,
    const float* __restrict__ prev, float* __restrict__ out)
{
    __shared__ char smem[34816];
    const long m0 = (long)blockIdx.y * 32;
    f32x4 acc[2][8];
    rows_core32(attnoutb + m0 * 512, 512, Wc, 512, smem, acc);

    const int tid = threadIdx.x, lane = tid & 63, w = tid >> 6;
    const int q = lane >> 4, c = lane & 15;
    float2* sred = (float2*)smem;        // [32][4]
#pragma unroll
    for (int m = 0; m < 2; m++)
#pragma unroll
        for (int r = 0; r < 4; r++) {
            float s = 0.f, qq = 0.f;
#pragma unroll
            for (int j = 0; j < 8; j++) {
                float v = acc[m][j][r]; s += v; qq += v * v;
            }
            s = xr_sum16(s); qq = xr_sum16(qq);
            if (c == 0) sred[(m * 16 + q * 4 + r) * 4 + w] = make_float2(s, qq);
        }
    __syncthreads();
#pragma unroll
    for (int m = 0; m < 2; m++)
#pragma unroll
        for (int r = 0; r < 4; r++) {
            int row = m * 16 + q * 4 + r;
            float s = 0.f, qq = 0.f;
#pragma unroll
            for (int ww = 0; ww < 4; ww++) {
                float2 t = sred[row * 4 + ww]; s += t.x; qq += t.y;
            }
            float mn = s * (1.f / 512);
            float rs = rsqrtf(qq * (1.f / 512) - mn * mn + LN_EPS);
            long rowg = m0 + row;
            float2 sh = stats[rowg];
#pragma unroll
            for (int j = 0; j < 8; j++) {
                int col = w * 128 + j * 16 + c;
                float t2 = (acc[m][j][r] - mn) * rs * g_c[col] + b_c[col];
                float t1 = __bfloat162float(h1n[rowg * 512 + col]);
                float hraw = __bfloat162float(preb[rowg * 1536 + 512 + col]);
                float hg = sigmoidf_((hraw - sh.x) * sh.y * g_pre[512 + col] +
                                     b_pre[512 + col]);
                float pv = prev[rowg * 512 + col];
                float o = tanhf(t1 + t2);
                out[rowg * 512 + col] = (1.f - hg) * o + hg * pv;
            }
        }
}

// =============== small kernels ==============================================
__global__ __launch_bounds__(256) void cvt4(
    const float* __restrict__ x, __hip_bfloat16* __restrict__ y, int n4)
{
    int i = blockIdx.x * 256 + threadIdx.x;
    if (i >= n4) return;
    float4 v = ((const float4*)x)[i];
    bfx4 o;
    o.x = __float2bfloat16(v.x); o.y = __float2bfloat16(v.y);
    o.z = __float2bfloat16(v.z); o.w = __float2bfloat16(v.w);
    ((bfx4*)y)[i] = o;
}

__global__ __launch_bounds__(256) void wtrans(
    const float* __restrict__ w0, const float* __restrict__ w1,
    const float* __restrict__ w2, const float* __restrict__ w3,
    const float* __restrict__ w4, __hip_bfloat16* __restrict__ WT)
{
    int z = blockIdx.z;
    const float* W; long off; int N;
    if (z == 0)      { W = w0; off = 0;                N = 1536; }
    else if (z == 1) { W = w1; off = 786432;           N = 512; }
    else if (z == 2) { W = w2; off = 786432 + 262144;  N = 512; }
    else if (z == 3) { W = w3; off = 786432 + 524288;  N = 512; }
    else             { W = w4; off = 786432 + 786432;  N = 512; }
    int n0 = blockIdx.x * 32, k0 = blockIdx.y * 32;
    if (n0 >= N) return;
    __shared__ float t[32][33];
    int tx = threadIdx.x & 31, ty = threadIdx.x >> 5;
#pragma unroll
    for (int i = 0; i < 4; i++)
        t[ty + i * 8][tx] = W[(long)(k0 + ty + i * 8) * N + n0 + tx];
    __syncthreads();
    __hip_bfloat16* O = WT + off;
#pragma unroll
    for (int i = 0; i < 4; i++)
        O[(long)(n0 + ty + i * 8) * 512 + k0 + tx] =
            __float2bfloat16(t[tx][ty + i * 8]);
}

__global__ __launch_bounds__(256) void ptrans(
    const __hip_bfloat16* __restrict__ src, __hip_bfloat16* __restrict__ dst)
{
    long boff = (long)blockIdx.z * (S_ * D_);
    int d0 = blockIdx.x * 32, s0 = blockIdx.y * 32;
    __shared__ __hip_bfloat16 t[32][34];
    int tx = threadIdx.x & 31, ty = threadIdx.x >> 5;
#pragma unroll
    for (int i = 0; i < 4; i++)
        t[ty + i * 8][tx] = src[boff + (long)(s0 + ty + i * 8) * D_ + d0 + tx];
    __syncthreads();
#pragma unroll
    for (int i = 0; i < 4; i++)
        dst[boff + (long)(d0 + ty + i * 8) * S_ + s0 + tx] = t[tx][ty + i * 8];
}

__global__ __launch_bounds__(256) void stats_fin(
    const float2* __restrict__ part, float2* __restrict__ stats)
{
    int r = blockIdx.x * 256 + threadIdx.x;
    float s = 0.f, qq = 0.f;
#pragma unroll
    for (int cb = 0; cb < 12; cb++) {
        float2 v = part[(long)cb * 16384 + r]; s += v.x; qq += v.y;
    }
    float m = s * (1.f / 1536);
    float rs = rsqrtf(qq * (1.f / 1536) - m * m + LN_EPS);
    stats[r] = make_float2(m, rs);
}

// ---------------- chunked SRU scan with inline LN ---------------------------
__global__ __launch_bounds__(256) void scan_part1(
    const __hip_bfloat16* __restrict__ preb, const float2* __restrict__ stats,
    const float* __restrict__ gpre, const float* __restrict__ bpre,
    float* __restrict__ Ap, float* __restrict__ Bp)
{
    int idx = blockIdx.x * 256 + threadIdx.x;   // b*512+d
    int b = idx >> 9, d = idx & 511;
    int ch = blockIdx.y;
    float gz = gpre[d], bz = bpre[d];
    float gp = gpre[1024 + d], bpv = bpre[1024 + d];
    float A = 1.f, s = 0.f;
    for (int t = ch * CT; t < (ch + 1) * CT; t++) {
        long row = (long)t * 32 + b;
        float2 st = stats[row];
        float zr = __bfloat162float(preb[row * 1536 + d]);
        float pr = __bfloat162float(preb[row * 1536 + 1024 + d]);
        float z = sigmoidf_((zr - st.x) * st.y * gz + bz);
        float pl = (pr - st.x) * st.y * gp + bpv;
        float a = 1.f - z;
        A *= a;
        s = a * s + z * pl;
    }
    Ap[ch * 16384 + idx] = A;
    Bp[ch * 16384 + idx] = s;
}

__global__ __launch_bounds__(256) void scan_part2(
    const float* __restrict__ Ap, const float* __restrict__ Bp,
    const float* __restrict__ h0, float* __restrict__ sin_,
    float* __restrict__ hlast)
{
    int idx = blockIdx.x * 256 + threadIdx.x;
    float s = h0[idx];
    for (int ch = 0; ch < NCH; ch++) {
        sin_[ch * 16384 + idx] = s;
        s = Ap[ch * 16384 + idx] * s + Bp[ch * 16384 + idx];
    }
    hlast[idx] = s;
}

__global__ __launch_bounds__(256) void scan_part3(
    const __hip_bfloat16* __restrict__ preb, const float2* __restrict__ stats,
    const float* __restrict__ gpre, const float* __restrict__ bpre,
    const float* __restrict__ sin_, __hip_bfloat16* __restrict__ ssb)
{
    int idx = blockIdx.x * 256 + threadIdx.x;
    int b = idx >> 9, d = idx & 511;
    int ch = blockIdx.y;
    float gz = gpre[d], bz = bpre[d];
    float gp = gpre[1024 + d], bpv = bpre[1024 + d];
    float s = sin_[ch * 16384 + idx];
    for (int t = ch * CT; t < (ch + 1) * CT; t++) {
        long row = (long)t * 32 + b;
        float2 st = stats[row];
        float zr = __bfloat162float(preb[row * 1536 + d]);
        float pr = __bfloat162float(preb[row * 1536 + 1024 + d]);
        float z = sigmoidf_((zr - st.x) * st.y * gz + bz);
        float pl = (pr - st.x) * st.y * gp + bpv;
        s += z * (pl - s);
        ssb[(long)t * 16384 + idx] = __float2bfloat16(s);
    }
}

extern "C" void kernel_launch(void* const* d_in, const int* in_sizes, int n_in,
                              void* d_out, int out_size, void* d_ws, size_t ws_size,
                              hipStream_t stream) {
    const float* prev  = (const float*)d_in[0];
    const float* hid0  = (const float*)d_in[1];
    const float* enc   = (const float*)d_in[2];
    const int*   mlen  = (const int*)  d_in[3];
    const float* W_in  = (const float*)d_in[4];
    const float* W_enc = (const float*)d_in[5];
    const float* W_att = (const float*)d_in[6];
    const float* W_hid = (const float*)d_in[7];
    const float* W_ctx = (const float*)d_in[8];
    const float* g_pre = (const float*)d_in[9];
    const float* b_pre = (const float*)d_in[10];
    const float* g_enc = (const float*)d_in[11];
    const float* b_enc = (const float*)d_in[12];
    const float* g_att = (const float*)d_in[13];
    const float* b_att = (const float*)d_in[14];
    const float* g_h   = (const float*)d_in[15];
    const float* b_h   = (const float*)d_in[16];
    const float* g_c   = (const float*)d_in[17];
    const float* b_c   = (const float*)d_in[18];

    float* out   = (float*)d_out;                 // [T,B,D]
    float* hlast = out + (long)T_ * B_ * D_;      // [B,D]
    float* pattn = hlast + (long)B_ * D_;         // [T,B,S]

    char* ws = (char*)d_ws;
    __hip_bfloat16* preb    = (__hip_bfloat16*)(ws);               // 48MB
    __hip_bfloat16* WT      = (__hip_bfloat16*)(ws + 50331648);    // 4MB
    __hip_bfloat16* prevb   = (__hip_bfloat16*)(ws + 54525952);    // 16MB
    __hip_bfloat16* encb    = (__hip_bfloat16*)(ws + 71303168);    // 16MB
    __hip_bfloat16* pctxb   = (__hip_bfloat16*)(ws + 88080384);    // 16MB
    __hip_bfloat16* pctxT   = (__hip_bfloat16*)(ws + 104857600);   // 16MB
    __hip_bfloat16* ssb     = (__hip_bfloat16*)(ws + 121634816);   // 16MB
    __hip_bfloat16* attninb = (__hip_bfloat16*)(ws + 138412032);   // 16MB
    __hip_bfloat16* pattnb  = (__hip_bfloat16*)(ws + 155189248);   // 16MB
    __hip_bfloat16* attnoutb= (__hip_bfloat16*)(ws + 171966464);   // 16MB
    __hip_bfloat16* h1n     = (__hip_bfloat16*)(ws + 188743680);   // 16MB
    float2* part            = (float2*)(ws + 205520896);           // 1.5MB
    float2* stats           = (float2*)(ws + 207093760);           // 128KB
    // scan buffers: each [NCH][16384] floats = 1 MB
    float* scanA            = (float*)(ws + 207224832);
    float* scanB            = (float*)(ws + 208273408);
    float* sinb             = (float*)(ws + 209321984);

    const __hip_bfloat16* W_encT = WT + 786432;
    const __hip_bfloat16* W_attT = WT + 786432 + 262144;
    const __hip_bfloat16* W_hidT = WT + 786432 + 524288;
    const __hip_bfloat16* W_ctxT = WT + 786432 + 786432;

    dim3 blk(256);

    // inputs -> bf16
    cvt4<<<8192, blk, 0, stream>>>(prev, prevb, 2097152);
    cvt4<<<8192, blk, 0, stream>>>(enc, encb, 2097152);
    wtrans<<<dim3(48, 16, 5), blk, 0, stream>>>(W_in, W_enc, W_att, W_hid,
                                                W_ctx, WT);

    // K1: preact GEMM -> preb bf16 + LN partials
    gemm_pre<<<dim3(12, 128), blk, 0, stream>>>(prevb, WT, preb, part);
    stats_fin<<<64, blk, 0, stream>>>(part, stats);

    // SRU scan (inline LN on preb)
    scan_part1<<<dim3(64, NCH), blk, 0, stream>>>(preb, stats, g_pre, b_pre,
                                                  scanA, scanB);
    scan_part2<<<64, blk, 0, stream>>>(scanA, scanB, hid0, sinb, hlast);
    scan_part3<<<dim3(64, NCH), blk, 0, stream>>>(preb, stats, g_pre, b_pre,
                                                  sinb, ssb);

    // K2: pctx = LN(enc @ W_enc) -> bf16 (+ transposed copy)
    gemm_ln<<<dim3(1, 512), blk, 0, stream>>>(encb, 512, W_encT, g_enc, b_enc,
                                              pctxb);
    ptrans<<<dim3(16, 16, 32), blk, 0, stream>>>(pctxb, pctxT);

    // K3: attn_in = LN(ss @ W_attn_in) -> bf16
    gemm_ln<<<dim3(1, 512), blk, 0, stream>>>(ssb, 512, W_attT, g_att, b_att,
                                              attninb);

    // K4: align + masked softmax -> pattn fp32 + pattnb bf16
    gemm_attn<<<dim3(1, 16, 32), blk, 0, stream>>>(attninb, pctxb, mlen,
                                                   pattn, pattnb);

    // K5: attn_out = av @ pctx / sqrt(d) -> bf16
    gemm_av<<<dim3(1, 16, 32), blk, 0, stream>>>(pattnb, pctxT, attnoutb);

    // K6: h1n = LN(ss @ W_hidden) -> bf16
    gemm_ln<<<dim3(1, 512), blk, 0, stream>>>(ssb, 512, W_hidT, g_h, b_h, h1n);

    // K7: out = (1-hg)*tanh(h1n + LN(attn_out @ W_ctx)) + hg*prev
    gemm_fin<<<dim3(1, 512), blk, 0, stream>>>(attnoutb, W_ctxT, h1n, preb,
                                               stats, g_c, b_c, g_pre, b_pre,
                                               prev, out);
}